// Round 4
// baseline (307.793 us; speedup 1.0000x reference)
//
#include <hip/hip_runtime.h>
#include <hip/hip_bf16.h>
#include <stdint.h>

namespace {

constexpr int MTOT = 8192;   // 4 * 2048 rows of x
constexpr int NTOT = 4096;   // OUT_DIM
constexpr int KTOT = 4096;   // IN_DIM

constexpr int BM = 256, BN = 256, BK = 64;
constexpr int NT = KTOT / BK;     // 64 K-tiles

typedef __attribute__((ext_vector_type(8))) short bf16x8;
typedef __attribute__((ext_vector_type(4))) float f32x4;

__device__ inline unsigned short to_bf16(float f) {
    union { float f; uint32_t u; } v; v.f = f;
    return (unsigned short)((v.u + 0x7FFFu + ((v.u >> 16) & 1u)) >> 16);
}

// ---- Kernel 1: fp32 -> bf16 convert of x (8 elems / thread) ----
__global__ __launch_bounds__(256) void convert_x_kernel(const float* __restrict__ x,
                                                        unsigned short* __restrict__ xb) {
    int idx = blockIdx.x * 256 + threadIdx.x;
    const f32x4* xv = reinterpret_cast<const f32x4*>(x);
    f32x4 v0 = xv[2 * idx];
    f32x4 v1 = xv[2 * idx + 1];
    union { bf16x8 v; unsigned short s[8]; } o;
    o.s[0] = to_bf16(v0.x); o.s[1] = to_bf16(v0.y);
    o.s[2] = to_bf16(v0.z); o.s[3] = to_bf16(v0.w);
    o.s[4] = to_bf16(v1.x); o.s[5] = to_bf16(v1.y);
    o.s[6] = to_bf16(v1.z); o.s[7] = to_bf16(v1.w);
    reinterpret_cast<bf16x8*>(xb)[idx] = o.v;
}

// ---- Kernel 2: W[o][i] = sum_b a[b][o/512][i/512] * s[b][o%512][i%512], bf16 out ----
__global__ __launch_bounds__(256) void gen_w_kernel(const float* __restrict__ a,
                                                    const float* __restrict__ s,
                                                    unsigned short* __restrict__ w) {
    int idx = blockIdx.x * 256 + threadIdx.x;   // 4096 * 512 threads
    int o  = idx >> 9;
    int i8 = idx & 511;
    int i0 = i8 * 8;
    int obig = o >> 9, orow = o & 511;
    int ibig = i0 >> 9, icol = i0 & 511;

    float acc[8];
#pragma unroll
    for (int j = 0; j < 8; ++j) acc[j] = 0.f;

#pragma unroll
    for (int b = 0; b < 8; ++b) {
        float av = a[b * 64 + obig * 8 + ibig];
        const f32x4* sv = reinterpret_cast<const f32x4*>(s + b * 512 * 512 + orow * 512 + icol);
        f32x4 s0 = sv[0], s1 = sv[1];
        acc[0] += av * s0.x; acc[1] += av * s0.y; acc[2] += av * s0.z; acc[3] += av * s0.w;
        acc[4] += av * s1.x; acc[5] += av * s1.y; acc[6] += av * s1.z; acc[7] += av * s1.w;
    }
    union { bf16x8 v; unsigned short q[8]; } ov;
#pragma unroll
    for (int j = 0; j < 8; ++j) ov.q[j] = to_bf16(acc[j]);
    reinterpret_cast<bf16x8*>(w)[idx] = ov.v;
}

// ---- Kernel 3: C[m,n] = sum_k A[m,k] * B[n,k] ----
// 256x256 tile, BK=64 split in kk-halves, 8 waves (2M x 4N), double buffer,
// 4 phases/K-tile (m201 8-phase template), counted vmcnt(4), XOR LDS swizzle.
__global__ __launch_bounds__(512, 2)
void gemm_bt_kernel(const unsigned short* __restrict__ A,
                    const unsigned short* __restrict__ B,
                    float* __restrict__ C) {
    // [buf][kk][row][col32] : 4 x 16 KiB per matrix = 128 KiB total
    __shared__ __align__(16) unsigned short As[2][2][BM][32];
    __shared__ __align__(16) unsigned short Bs[2][2][BN][32];

    // XCD-aware bijective swizzle: 512 blocks, 8 XCDs, 64 blocks/XCD
    int bid = blockIdx.x;
    int swz = (bid & 7) * 64 + (bid >> 3);
    int bm = swz >> 4;                 // 16 bn-tiles per bm-row
    int bn = swz & 15;

    int tid  = threadIdx.x;
    int wid  = tid >> 6;               // 0..7
    int lane = tid & 63;
    int wm = wid >> 2, wn = wid & 3;   // wave owns 128x64 of C

    // ---- staging geometry: row = 64 B = 4 lanes of 16 B; 16 rows/gload/wave ----
    int srow = lane >> 2;                              // 0..15
    int sq   = (lane & 3) ^ ((lane >> 3) & 3);         // pre-swizzled 16B slot
    const unsigned short* ag0 = A + (size_t)(bm * BM +       wid * 16 + srow) * KTOT + sq * 8;
    const unsigned short* ag1 = A + (size_t)(bm * BM + 128 + wid * 16 + srow) * KTOT + sq * 8;
    const unsigned short* bg0 = B + (size_t)(bn * BN +       wid * 16 + srow) * KTOT + sq * 8;
    const unsigned short* bg1 = B + (size_t)(bn * BN + 128 + wid * 16 + srow) * KTOT + sq * 8;

    // ---- fragment-read geometry (same XOR on read side) ----
    int rl = lane & 15;
    int rq = (lane >> 4) ^ ((rl >> 1) & 3);            // swizzled 16B slot, 0..3

    f32x4 acc[8][4];
#pragma unroll
    for (int m = 0; m < 8; ++m)
#pragma unroll
        for (int n = 0; n < 4; ++n) acc[m][n] = (f32x4)0.f;

    auto STAGE_A = [&](int pb, int kk, int koff) {
        __builtin_amdgcn_global_load_lds(
            (const __attribute__((address_space(1))) void*)(ag0 + koff + kk * 32),
            (__attribute__((address_space(3))) void*)&As[pb][kk][wid * 16][0], 16, 0, 0);
        __builtin_amdgcn_global_load_lds(
            (const __attribute__((address_space(1))) void*)(ag1 + koff + kk * 32),
            (__attribute__((address_space(3))) void*)&As[pb][kk][128 + wid * 16][0], 16, 0, 0);
    };
    auto STAGE_B = [&](int pb, int kk, int koff) {
        __builtin_amdgcn_global_load_lds(
            (const __attribute__((address_space(1))) void*)(bg0 + koff + kk * 32),
            (__attribute__((address_space(3))) void*)&Bs[pb][kk][wid * 16][0], 16, 0, 0);
        __builtin_amdgcn_global_load_lds(
            (const __attribute__((address_space(1))) void*)(bg1 + koff + kk * 32),
            (__attribute__((address_space(3))) void*)&Bs[pb][kk][128 + wid * 16][0], 16, 0, 0);
    };

    // ---- prologue: stage tile 0 (4 halves, 8 loads); drain to 4 (Ak0,Bk0 ready) ----
    STAGE_A(0, 0, 0); STAGE_B(0, 0, 0);
    STAGE_A(0, 1, 0); STAGE_B(0, 1, 0);
    asm volatile("s_waitcnt vmcnt(4)" ::: "memory");
    __builtin_amdgcn_s_barrier();

    // ---- main loop: 64 K-tiles, unrolled x2 for compile-time buffer parity ----
    for (int tt = 0; tt < NT; tt += 2) {
#pragma unroll
        for (int u = 0; u < 2; ++u) {
            int t = tt + u;
            int tn = t + 1; if (tn > NT - 1) tn = NT - 1;   // tail: redundant restage, never read
            int koff = tn * BK;
            const int p = u;            // t & 1
            bf16x8 bfr0[4], bfr1[4];

            // ---- PH1: A(k0) m0-3 + B(k0) n0-3 reads; stage A-k0(t+1); MFMA q(m0-3,k0) ----
            {
                bf16x8 afr[4];
#pragma unroll
                for (int m = 0; m < 4; ++m)
                    afr[m] = *reinterpret_cast<const bf16x8*>(&As[p][0][wm * 128 + m * 16 + rl][rq * 8]);
#pragma unroll
                for (int n = 0; n < 4; ++n)
                    bfr0[n] = *reinterpret_cast<const bf16x8*>(&Bs[p][0][wn * 64 + n * 16 + rl][rq * 8]);
                STAGE_A(p ^ 1, 0, koff);
                __builtin_amdgcn_s_barrier();
                asm volatile("s_waitcnt lgkmcnt(0)" ::: "memory");
                __builtin_amdgcn_sched_barrier(0);
                __builtin_amdgcn_s_setprio(1);
#pragma unroll
                for (int m = 0; m < 4; ++m)
#pragma unroll
                    for (int n = 0; n < 4; ++n)
                        acc[m][n] = __builtin_amdgcn_mfma_f32_16x16x32_bf16(afr[m], bfr0[n], acc[m][n], 0, 0, 0);
                __builtin_amdgcn_s_setprio(0);
                __builtin_amdgcn_s_barrier();
            }
            // ---- PH2: A(k0) m4-7 reads (B reused); stage B-k0(t+1); MFMA q(m4-7,k0) ----
            {
                bf16x8 afr[4];
#pragma unroll
                for (int m = 0; m < 4; ++m)
                    afr[m] = *reinterpret_cast<const bf16x8*>(&As[p][0][wm * 128 + (m + 4) * 16 + rl][rq * 8]);
                STAGE_B(p ^ 1, 0, koff);
                __builtin_amdgcn_s_barrier();
                asm volatile("s_waitcnt lgkmcnt(0)" ::: "memory");
                __builtin_amdgcn_sched_barrier(0);
                __builtin_amdgcn_s_setprio(1);
#pragma unroll
                for (int m = 0; m < 4; ++m)
#pragma unroll
                    for (int n = 0; n < 4; ++n)
                        acc[m + 4][n] = __builtin_amdgcn_mfma_f32_16x16x32_bf16(afr[m], bfr0[n], acc[m + 4][n], 0, 0, 0);
                __builtin_amdgcn_s_setprio(0);
                // gate for PH3/PH4 reads of A-k1(t), B-k1(t): keep A-k0,B-k0(t+1) in flight
                asm volatile("s_waitcnt vmcnt(4)" ::: "memory");
                __builtin_amdgcn_s_barrier();
            }
            // ---- PH3: A(k1) m0-3 + B(k1) n0-3 reads; stage A-k1(t+1); MFMA q(m0-3,k1) ----
            {
                bf16x8 afr[4];
#pragma unroll
                for (int m = 0; m < 4; ++m)
                    afr[m] = *reinterpret_cast<const bf16x8*>(&As[p][1][wm * 128 + m * 16 + rl][rq * 8]);
#pragma unroll
                for (int n = 0; n < 4; ++n)
                    bfr1[n] = *reinterpret_cast<const bf16x8*>(&Bs[p][1][wn * 64 + n * 16 + rl][rq * 8]);
                STAGE_A(p ^ 1, 1, koff);
                __builtin_amdgcn_s_barrier();
                asm volatile("s_waitcnt lgkmcnt(0)" ::: "memory");
                __builtin_amdgcn_sched_barrier(0);
                __builtin_amdgcn_s_setprio(1);
#pragma unroll
                for (int m = 0; m < 4; ++m)
#pragma unroll
                    for (int n = 0; n < 4; ++n)
                        acc[m][n] = __builtin_amdgcn_mfma_f32_16x16x32_bf16(afr[m], bfr1[n], acc[m][n], 0, 0, 0);
                __builtin_amdgcn_s_setprio(0);
                __builtin_amdgcn_s_barrier();
            }
            // ---- PH4: A(k1) m4-7 reads; stage B-k1(t+1); MFMA q(m4-7,k1) ----
            {
                bf16x8 afr[4];
#pragma unroll
                for (int m = 0; m < 4; ++m)
                    afr[m] = *reinterpret_cast<const bf16x8*>(&As[p][1][wm * 128 + (m + 4) * 16 + rl][rq * 8]);
                STAGE_B(p ^ 1, 1, koff);
                __builtin_amdgcn_s_barrier();
                asm volatile("s_waitcnt lgkmcnt(0)" ::: "memory");
                __builtin_amdgcn_sched_barrier(0);
                __builtin_amdgcn_s_setprio(1);
#pragma unroll
                for (int m = 0; m < 4; ++m)
#pragma unroll
                    for (int n = 0; n < 4; ++n)
                        acc[m + 4][n] = __builtin_amdgcn_mfma_f32_16x16x32_bf16(afr[m], bfr1[n], acc[m + 4][n], 0, 0, 0);
                __builtin_amdgcn_s_setprio(0);
                // gate for next tile's PH1/PH2 reads of A-k0,B-k0(t+1)
                asm volatile("s_waitcnt vmcnt(4)" ::: "memory");
                __builtin_amdgcn_s_barrier();
            }
        }
    }
    asm volatile("s_waitcnt vmcnt(0)" ::: "memory");

    // ---- C write: per 16x16 frag, col = lane&15, row = (lane>>4)*4 + j ----
    int crow0 = bm * BM + wm * 128 + (lane >> 4) * 4;
    int ccol0 = bn * BN + wn * 64 + (lane & 15);
#pragma unroll
    for (int m = 0; m < 8; ++m)
#pragma unroll
        for (int n = 0; n < 4; ++n)
#pragma unroll
            for (int j = 0; j < 4; ++j) {
                size_t r = (size_t)(crow0 + m * 16 + j);
                size_t c = (size_t)(ccol0 + n * 16);
                C[r * NTOT + c] = acc[m][n][j];
            }
}

} // anonymous namespace

extern "C" void kernel_launch(void* const* d_in, const int* in_sizes, int n_in,
                              void* d_out, int out_size, void* d_ws, size_t ws_size,
                              hipStream_t stream) {
    const float* x = (const float*)d_in[0];   // (4,2048,4096) f32
    const float* a = (const float*)d_in[1];   // (8,8,8) f32
    const float* s = (const float*)d_in[2];   // (8,512,512) f32
    float* out = (float*)d_out;               // (4,2048,4096) f32

    unsigned short* xb = (unsigned short*)d_ws;                    // 64 MiB bf16 x
    unsigned short* wb = xb + (size_t)MTOT * KTOT;                 // 32 MiB bf16 W

    convert_x_kernel<<<(MTOT * KTOT / 8) / 256, 256, 0, stream>>>(x, xb);
    gen_w_kernel<<<(NTOT * KTOT / 8) / 256, 256, 0, stream>>>(a, s, wb);
    gemm_bt_kernel<<<(MTOT / 256) * (NTOT / 256), 512, 0, stream>>>(xb, wb, out);
}